// Round 19
// baseline (215.691 us; speedup 1.0000x reference)
//
#include <hip/hip_runtime.h>

#define NN 10000    // nodes
#define RR 100      // relations
#define EE 5000     // edges per relation
#define D0 2048
#define D1 128
#define D2 64
#define D3 20
#define NE (RR*EE)  // 500000 edges total
#define MAXD 128    // fixed CSR stride per node (true max total deg ~80)

using short8  = __attribute__((ext_vector_type(8))) short;
using float4e = __attribute__((ext_vector_type(4))) float;

typedef const __attribute__((address_space(1))) void g_void;
typedef __attribute__((address_space(3))) void l_void;

__device__ __forceinline__ unsigned short f2bf(float f) {
  unsigned int u = __float_as_uint(f);
  unsigned int r = u + 0x7fffu + ((u >> 16) & 1u);   // RNE
  return (unsigned short)(r >> 16);
}
__device__ __forceinline__ float bf2f(unsigned short u) {
  return __uint_as_float(((unsigned int)u) << 16);
}
__device__ __forceinline__ unsigned int pk2(float lo, float hi) {
  return ((unsigned int)f2bf(hi) << 16) | (unsigned int)f2bf(lo);
}

// ---------------------------------------------------------------------------
// prep: fused {zero cur, wtrans, wc1t, wc2t} (A-touch deleted: rounds 16/17
// proved it costs ~10us and delivers nothing — slow in-graph gemm0 is HBM
// contention with the harness's concurrent 327MB re-poison fill, not cold L3).
// ---------------------------------------------------------------------------
#define CURB 10             // 2,504 int4 zeros (cur)
#define WTBLK 1024          // 262,144 elems
#define W1BLK 288           // 73,728 elems
#define W2BLK 72            // 18,432 elems
__global__ __launch_bounds__(256) void prep_kernel(
    const float* __restrict__ W, const float* __restrict__ root1,
    const float* __restrict__ basis1, const float* __restrict__ root2,
    const float* __restrict__ basis2, int4* __restrict__ cur4,
    unsigned short* __restrict__ Btw, unsigned short* __restrict__ Wc1T,
    unsigned short* __restrict__ Wc2T) {
  const int b = blockIdx.x, tid = threadIdx.x;
  if (b < CURB) {
    int i = b * 256 + tid;
    if (i < 2504) cur4[i] = make_int4(0, 0, 0, 0);
  } else if (b < CURB + WTBLK) {
    int idx = (b - CURB) * 256 + tid;                 // 128*2048, exact
    int n = idx >> 11, k = idx & 2047;
    Btw[idx] = f2bf(W[(size_t)k * 128 + n]);
  } else if (b < CURB + WTBLK + W1BLK) {
    int idx = (b - CURB - WTBLK) * 256 + tid;         // 64*1152, exact
    int o = idx / 1152, j = idx - o * 1152;
    float v = (j < 128) ? root1[j * 64 + o] : basis1[(j - 128) * 64 + o];
    Wc1T[idx] = f2bf(v);
  } else {
    int idx = (b - CURB - WTBLK - W1BLK) * 256 + tid; // 32*576, exact
    int c = idx / 576, j = idx - c * 576;
    float v = 0.f;
    if (c < 20) v = (j < 64) ? root2[j * 20 + c] : basis2[(j - 64) * 20 + c];
    Wc2T[idx] = f2bf(v);
  }
}

// ---------------------------------------------------------------------------
// scatter: ONE random 4B store per edge (rec only).
// ---------------------------------------------------------------------------
__global__ void scatter_kernel(const int* __restrict__ ei,
                               int* __restrict__ cur, int* __restrict__ rec) {
  int gid = blockIdx.x * 256 + threadIdx.x;
  if (gid >= NE) return;
  int r = gid / EE, e = gid - r * EE;
  int s = ei[r * 2 * EE + e];
  int d = ei[r * 2 * EE + EE + e];
  int p = atomicAdd(&cur[d], 1);
  if (p < MAXD) rec[d * MAXD + p] = (r << 14) | s;
}

// ---------------------------------------------------------------------------
// gemm0 — counted-vmcnt pipeline (round-11 version): xb = bf16(A @ W).
// Tile M=16, N=128, BK=64 (32 steps). 625 blocks, 52KB LDS, 3/CU.
// ---------------------------------------------------------------------------
__global__ __launch_bounds__(256, 3) void gemm0_mfma(
    const float* __restrict__ A, const unsigned short* __restrict__ Btw,
    unsigned short* __restrict__ xb) {
  __shared__ __align__(16) unsigned short Asb[2][16 * 64];    // 2 x 2 KB
  __shared__ __align__(16) unsigned short Bsb[3][128 * 64];   // 3 x 16 KB
  const int tid = threadIdx.x;
  const int m0 = blockIdx.x * 16;
  const int wv = tid >> 6, lane = tid & 63;
  const int lrow = lane & 15, quad = lane >> 4;

  const int ar = tid >> 4, ag = tid & 15;
  const float* Ap = &A[(size_t)(m0 + ar) * D0 + ag * 4];
  const int aw = (ar * 128 + ((ag * 8) ^ ((ar & 7) << 4))) >> 1;  // ushort idx

  const int rowB = wv * 32 + (lane >> 3);
  const int gch  = (lane & 7) ^ (lane >> 3);
  const unsigned short* BgBase = &Btw[(size_t)rowB * D0 + gch * 8];
  const int ldsB = wv * 2048;   // ushort idx of this wave's 4KB region

  float4 a0, a1;

#define G0_LOADB(buf, c)                                                     \
  { _Pragma("unroll")                                                        \
    for (int i = 0; i < 4; i++) {                                            \
      __builtin_amdgcn_global_load_lds(                                      \
          (g_void*)(BgBase + (size_t)i * 8 * D0 + (c) * 64),                 \
          (l_void*)&Bsb[buf][ldsB + i * 512], 16, 0, 0);                     \
    } }

#define G0_LOADA(reg, c)  { reg = *(const float4*)(Ap + (c) * 64); }

#define G0_PACKA(reg, buf)                                              \
  { uint2 p0;                                                           \
    p0.x = pk2(reg.x, reg.y); p0.y = pk2(reg.z, reg.w);                 \
    *(uint2*)&Asb[buf][aw] = p0; }

#define G0_COMPUTE(abuf, bbuf)                                          \
  { const int aswz = (lrow & 7) << 4;                                   \
    _Pragma("unroll")                                                   \
    for (int kk = 0; kk < 2; kk++) {                                    \
      short8 af = *(const short8*)&Asb[abuf][(lrow * 128 + ((quad * 16 + kk * 64) ^ aswz)) >> 1]; \
      _Pragma("unroll")                                                 \
      for (int nt = 0; nt < 2; nt++) {                                  \
        const int brow = wv * 32 + nt * 16 + lrow;                      \
        short8 bfr = *(const short8*)&Bsb[bbuf][(brow * 128 + ((quad * 16 + kk * 64) ^ ((brow & 7) << 4))) >> 1]; \
        acc[nt] = __builtin_amdgcn_mfma_f32_16x16x32_bf16(af, bfr, acc[nt], 0, 0, 0); \
      }                                                                 \
    } }

  float4e acc[2];
#pragma unroll
  for (int i = 0; i < 2; i++) { acc[i][0]=0.f; acc[i][1]=0.f; acc[i][2]=0.f; acc[i][3]=0.f; }

  G0_LOADA(a0, 0);
  G0_LOADB(0, 0);
  G0_LOADB(1, 1);
  G0_PACKA(a0, 0);
  G0_LOADA(a1, 1);
  asm volatile("s_waitcnt vmcnt(5) lgkmcnt(0)\ns_barrier" ::: "memory");

#pragma unroll
  for (int c = 0; c < 32; c++) {
    if (c <= 29) {
      G0_LOADB((c + 2) % 3, c + 2);
      if ((c & 1) == 0) { G0_LOADA(a0, c + 2); }
      else              { G0_LOADA(a1, c + 2); }
      __builtin_amdgcn_sched_barrier(0);
    }
    G0_COMPUTE(c & 1, c % 3);
    if (c <= 30) {
      if (((c + 1) & 1) == 0) { G0_PACKA(a0, 0); }
      else                    { G0_PACKA(a1, 1); }
      asm volatile("s_waitcnt vmcnt(5) lgkmcnt(0)\ns_barrier" ::: "memory");
    }
  }

#pragma unroll
  for (int nt = 0; nt < 2; nt++) {
    const int col = wv * 32 + nt * 16 + lrow;
#pragma unroll
    for (int r = 0; r < 4; r++) {
      const int row = m0 + quad * 4 + r;
      xb[(size_t)row * D1 + col] = f2bf(acc[nt][r]);
    }
  }
}

// ---------------------------------------------------------------------------
// agg1e: A1b[n, b*128+i] = bf16( sum_{e->n} esc_e*comp1[r_e,b]*x[src_e,i] )
// esc via per-wave LDS relation histogram (in-kernel).
// *** THIS ROUND: launched 3x (idempotent) as a measurement probe:
// *** g1 = (total - 147.6)/2.
// ---------------------------------------------------------------------------
__global__ __launch_bounds__(256) void agg1e_kernel(
    const unsigned short* __restrict__ xb, const int* __restrict__ cur,
    const int* __restrict__ rec, const float* __restrict__ comp,
    unsigned short* __restrict__ A1b) {
  __shared__ float s_comp[RR * 8];
  __shared__ float s_rcp[4][RR];
  const int tid = threadIdx.x;
  for (int i = tid; i < RR * 8; i += 256) s_comp[i] = comp[i];
  const int wv = tid >> 6, lane = tid & 63;
  const int n = blockIdx.x * 4 + wv;          // always < NN (grid exact)
  int* hist = (int*)&s_rcp[wv][0];
  for (int i = lane; i < RR; i += 64) hist[i] = 0;
  __syncthreads();
  int cnt = cur[n]; if (cnt > MAXD) cnt = MAXD;
  if (lane < cnt)      atomicAdd(&hist[rec[n * MAXD + lane] >> 14], 1);
  if (lane + 64 < cnt) atomicAdd(&hist[rec[n * MAXD + lane + 64] >> 14], 1);
  __syncthreads();
  for (int i = lane; i < RR; i += 64) {
    int h = hist[i];
    s_rcp[wv][i] = 1.0f / (float)h;
  }
  __syncthreads();

  float acc[8][2];
#pragma unroll
  for (int b = 0; b < 8; b++) { acc[b][0] = 0.f; acc[b][1] = 0.f; }
  const int beg = n * MAXD, end = beg + cnt;
  int idx = beg;
  for (; idx + 3 < end; idx += 4) {
    int rc[4]; float sc[4]; unsigned int xv[4];
#pragma unroll
    for (int u = 0; u < 4; u++) rc[u] = rec[idx + u];
#pragma unroll
    for (int u = 0; u < 4; u++) sc[u] = s_rcp[wv][rc[u] >> 14];
#pragma unroll
    for (int u = 0; u < 4; u++)
      xv[u] = *(const unsigned int*)&xb[(size_t)(rc[u] & 16383) * D1 + lane * 2];
#pragma unroll
    for (int u = 0; u < 4; u++) {
      const float* cb = &s_comp[(rc[u] >> 14) * 8];
      float x0 = __uint_as_float((xv[u] & 0xffffu) << 16);
      float x1 = __uint_as_float(xv[u] & 0xffff0000u);
#pragma unroll
      for (int b = 0; b < 8; b++) {
        float w = sc[u] * cb[b];
        acc[b][0] += w * x0;
        acc[b][1] += w * x1;
      }
    }
  }
  for (; idx < end; idx++) {
    int rc = rec[idx];
    float sc = s_rcp[wv][rc >> 14];
    unsigned int xv = *(const unsigned int*)&xb[(size_t)(rc & 16383) * D1 + lane * 2];
    const float* cb = &s_comp[(rc >> 14) * 8];
    float x0 = __uint_as_float((xv & 0xffffu) << 16);
    float x1 = __uint_as_float(xv & 0xffff0000u);
#pragma unroll
    for (int b = 0; b < 8; b++) {
      float w = sc * cb[b];
      acc[b][0] += w * x0;
      acc[b][1] += w * x1;
    }
  }
#pragma unroll
  for (int b = 0; b < 8; b++) {
    ushort2 o; o.x = f2bf(acc[b][0]); o.y = f2bf(acc[b][1]);
    *(ushort2*)&A1b[(size_t)n * 1024 + b * 128 + lane * 2] = o;
  }
}

// ---------------------------------------------------------------------------
// agg2e: A2b[n, b*64+i] = bf16( sum_{e->n} esc_e*comp2[r_e,b]*h[src_e,i] )
// ---------------------------------------------------------------------------
__global__ __launch_bounds__(256) void agg2e_kernel(
    const unsigned short* __restrict__ hb, const int* __restrict__ cur,
    const int* __restrict__ rec, const float* __restrict__ comp,
    unsigned short* __restrict__ A2b) {
  __shared__ float s_comp[RR * 8];
  __shared__ float s_rcp[4][RR];
  const int tid = threadIdx.x;
  for (int i = tid; i < RR * 8; i += 256) s_comp[i] = comp[i];
  const int wv = tid >> 6, lane = tid & 63;
  const int n = blockIdx.x * 4 + wv;          // always < NN
  int* hist = (int*)&s_rcp[wv][0];
  for (int i = lane; i < RR; i += 64) hist[i] = 0;
  __syncthreads();
  int cnt = cur[n]; if (cnt > MAXD) cnt = MAXD;
  if (lane < cnt)      atomicAdd(&hist[rec[n * MAXD + lane] >> 14], 1);
  if (lane + 64 < cnt) atomicAdd(&hist[rec[n * MAXD + lane + 64] >> 14], 1);
  __syncthreads();
  for (int i = lane; i < RR; i += 64) {
    int h = hist[i];
    s_rcp[wv][i] = 1.0f / (float)h;
  }
  __syncthreads();

  float acc[8];
#pragma unroll
  for (int b = 0; b < 8; b++) acc[b] = 0.f;
  const int beg = n * MAXD, end = beg + cnt;
  int idx = beg;
  for (; idx + 3 < end; idx += 4) {
    int rc[4]; float sc[4]; float hv[4];
#pragma unroll
    for (int u = 0; u < 4; u++) rc[u] = rec[idx + u];
#pragma unroll
    for (int u = 0; u < 4; u++) sc[u] = s_rcp[wv][rc[u] >> 14];
#pragma unroll
    for (int u = 0; u < 4; u++)
      hv[u] = bf2f(hb[(size_t)(rc[u] & 16383) * D2 + lane]);
#pragma unroll
    for (int u = 0; u < 4; u++) {
      const float* cb = &s_comp[(rc[u] >> 14) * 8];
#pragma unroll
      for (int b = 0; b < 8; b++) acc[b] += sc[u] * cb[b] * hv[u];
    }
  }
  for (; idx < end; idx++) {
    int rc = rec[idx];
    float sc = s_rcp[wv][rc >> 14];
    float hv = bf2f(hb[(size_t)(rc & 16383) * D2 + lane]);
    const float* cb = &s_comp[(rc >> 14) * 8];
#pragma unroll
    for (int b = 0; b < 8; b++) acc[b] += sc * cb[b] * hv;
  }
#pragma unroll
  for (int b = 0; b < 8; b++)
    A2b[(size_t)n * 512 + b * 64 + lane] = f2bf(acc[b]);
}

// ---------------------------------------------------------------------------
// hlayer: hb = bf16(relu([xb|A1b](K=1152) @ Wc1T + bias1))
// ---------------------------------------------------------------------------
__global__ __launch_bounds__(256) void hlayer_mfma(
    const unsigned short* __restrict__ xb, const unsigned short* __restrict__ A1b,
    const unsigned short* __restrict__ Wt, const float* __restrict__ bias1,
    unsigned short* __restrict__ hb) {
  __shared__ __align__(16) unsigned short Asb[2][32 * 64];   // 8 KB
  __shared__ __align__(16) unsigned short Bsb[2][64 * 64];   // 16 KB
  const int tid = threadIdx.x;
  const int m0 = blockIdx.x * 32;
  const int wv = tid >> 6, lane = tid & 63;
  const int lrow = lane & 15, quad = lane >> 4;
  const int mt = wv >> 1, nb = wv & 1;    // wave: 16 rows x 32 cols

  const int ar = tid >> 3, ac = tid & 7;
  int gr = m0 + ar; if (gr >= NN) gr = NN - 1;
  const unsigned short* Ax = &xb[(size_t)gr * D1 + ac * 8];     // steps 0-1
  const unsigned short* Aa = &A1b[(size_t)gr * 1024 + ac * 8];  // steps 2-17
  const int asw = (ar & 7) << 4;
  const int aw = (ar * 128 + ((ac * 16) ^ asw)) >> 1;

  const int br = tid >> 2, bq = tid & 3;
  const unsigned short* Bp = &Wt[(size_t)br * 1152 + bq * 16];
  const int bsw = (br & 7) << 4;
  const int bw0 = (br * 128 + ((bq * 32) ^ bsw)) >> 1;
  const int bw1 = (br * 128 + ((bq * 32 + 16) ^ bsw)) >> 1;

  uint4 ra, rb0, rb1;

#define H_LOADG(c)                                                       \
  { int kb = (c) * 64;                                                   \
    ra  = (kb < 128) ? *(const uint4*)(Ax + kb)                          \
                     : *(const uint4*)(Aa + (kb - 128));                 \
    rb0 = *(const uint4*)(Bp + kb);                                      \
    rb1 = *(const uint4*)(Bp + kb + 8); }

#define H_STOREL(buf)                                                    \
  { *(uint4*)&Asb[buf][aw]  = ra;                                        \
    *(uint4*)&Bsb[buf][bw0] = rb0;                                       \
    *(uint4*)&Bsb[buf][bw1] = rb1; }

#define H_COMPUTE(buf)                                                   \
  { const int arow = mt * 16 + lrow;                                     \
    const int aswz = (arow & 7) << 4;                                    \
    _Pragma("unroll")                                                    \
    for (int kk = 0; kk < 2; kk++) {                                     \
      short8 af = *(const short8*)&Asb[buf][(arow * 128 + ((quad * 16 + kk * 64) ^ aswz)) >> 1]; \
      _Pragma("unroll")                                                  \
      for (int nt = 0; nt < 2; nt++) {                                   \
        const int brow = nb * 32 + nt * 16 + lrow;                       \
        short8 bfr = *(const short8*)&Bsb[buf][(brow * 128 + ((quad * 16 + kk * 64) ^ ((brow & 7) << 4))) >> 1]; \
        acc[nt] = __builtin_amdgcn_mfma_f32_16x16x32_bf16(af, bfr, acc[nt], 0, 0, 0); \
      }                                                                  \
    } }

  float4e acc[2];
#pragma unroll
  for (int i = 0; i < 2; i++) { acc[i][0]=0.f; acc[i][1]=0.f; acc[i][2]=0.f; acc[i][3]=0.f; }

  H_LOADG(0);
  H_STOREL(0);
  __syncthreads();

#pragma unroll
  for (int c = 0; c < 18; c++) {
    if (c < 17) {
      H_LOADG(c + 1);
      __builtin_amdgcn_sched_barrier(0);   // pin prefetch before compute
    }
    H_COMPUTE(c & 1);
    if (c < 17) H_STOREL((c + 1) & 1);
    __syncthreads();
  }

#pragma unroll
  for (int nt = 0; nt < 2; nt++) {
    int col = nb * 32 + nt * 16 + lrow;
    float bv = bias1[col];
#pragma unroll
    for (int r = 0; r < 4; r++) {
      int row = m0 + mt * 16 + quad * 4 + r;
      if (row < NN)
        hb[(size_t)row * D2 + col] = f2bf(fmaxf(acc[nt][r] + bv, 0.f));
    }
  }
}

// ---------------------------------------------------------------------------
// out: out = [hb|A2b](K=576) @ Wc2T + bias2
// ---------------------------------------------------------------------------
__global__ __launch_bounds__(256) void out_mfma(
    const unsigned short* __restrict__ hb, const unsigned short* __restrict__ A2b,
    const unsigned short* __restrict__ Wt, const float* __restrict__ bias2,
    float* __restrict__ out) {
  __shared__ __align__(16) unsigned short Asb[2][32 * 64];   // 8 KB
  __shared__ __align__(16) unsigned short Bsb[2][32 * 64];   // 8 KB
  const int tid = threadIdx.x;
  const int m0 = blockIdx.x * 32;
  const int wv = tid >> 6, lane = tid & 63;
  const int lrow = lane & 15, quad = lane >> 4;
  const int mt = wv >> 1, ntn = wv & 1;   // wave: 16 rows x 16 cols

  const int ar = tid >> 3, ac = tid & 7;
  int gr = m0 + ar; if (gr >= NN) gr = NN - 1;
  const unsigned short* Ah = &hb[(size_t)gr * D2 + ac * 8];     // step 0
  const unsigned short* Aa = &A2b[(size_t)gr * 512 + ac * 8];   // steps 1-8
  const unsigned short* Bp = &Wt[(size_t)ar * 576 + ac * 8];
  const int asw = (ar & 7) << 4;
  const int aw = (ar * 128 + ((ac * 16) ^ asw)) >> 1;

  uint4 ra, rb;

#define O_LOADG(c)                                                       \
  { int kb = (c) * 64;                                                   \
    ra = (kb < 64) ? *(const uint4*)(Ah)                                 \
                   : *(const uint4*)(Aa + (kb - 64));                    \
    rb = *(const uint4*)(Bp + kb); }

#define O_STOREL(buf)                                                    \
  { *(uint4*)&Asb[buf][aw] = ra;                                         \
    *(uint4*)&Bsb[buf][aw] = rb; }

#define O_COMPUTE(buf)                                                   \
  { const int arow = mt * 16 + lrow;                                     \
    const int aswz = (arow & 7) << 4;                                    \
    const int brow = ntn * 16 + lrow;                                    \
    const int bswz = (brow & 7) << 4;                                    \
    _Pragma("unroll")                                                    \
    for (int kk = 0; kk < 2; kk++) {                                     \
      short8 af = *(const short8*)&Asb[buf][(arow * 128 + ((quad * 16 + kk * 64) ^ aswz)) >> 1]; \
      short8 bfr = *(const short8*)&Bsb[buf][(brow * 128 + ((quad * 16 + kk * 64) ^ bswz)) >> 1]; \
      acc = __builtin_amdgcn_mfma_f32_16x16x32_bf16(af, bfr, acc, 0, 0, 0); \
    } }

  float4e acc;
  acc[0]=0.f; acc[1]=0.f; acc[2]=0.f; acc[3]=0.f;

  O_LOADG(0);
  O_STOREL(0);
  __syncthreads();

#pragma unroll
  for (int c = 0; c < 9; c++) {
    if (c < 8) {
      O_LOADG(c + 1);
      __builtin_amdgcn_sched_barrier(0);   // pin prefetch before compute
    }
    O_COMPUTE(c & 1);
    if (c < 8) O_STOREL((c + 1) & 1);
    __syncthreads();
  }

  int col = ntn * 16 + lrow;
  if (col < D3) {
    float bv = bias2[col];
#pragma unroll
    for (int r = 0; r < 4; r++) {
      int row = m0 + mt * 16 + quad * 4 + r;
      if (row < NN)
        out[(size_t)row * D3 + col] = acc[r] + bv;
    }
  }
}

// ---------------------------------------------------------------------------
extern "C" void kernel_launch(void* const* d_in, const int* in_sizes, int n_in,
                              void* d_out, int out_size, void* d_ws,
                              size_t ws_size, hipStream_t stream) {
  const float* x_drug = (const float*)d_in[0];
  const float* drug_w = (const float*)d_in[1];
  const int*   ei     = (const int*)d_in[2];
  const float* basis1 = (const float*)d_in[3];
  const float* comp1  = (const float*)d_in[4];
  const float* root1  = (const float*)d_in[5];
  const float* bias1  = (const float*)d_in[6];
  const float* basis2 = (const float*)d_in[7];
  const float* comp2  = (const float*)d_in[8];
  const float* root2  = (const float*)d_in[9];
  const float* bias2  = (const float*)d_in[10];
  float* out = (float*)d_out;

  float* ws = (float*)d_ws;
  int*   cur  = (int*)ws;                          // 10,016
  int*   rec  = cur + 10016;                       // 1,280,000 (NN*MAXD)
  unsigned short* xb   = (unsigned short*)(rec + NN * MAXD);       // 640,000 f
  unsigned short* hb   = (unsigned short*)((float*)xb + 640000);   // 320,000 f
  unsigned short* Btw  = (unsigned short*)((float*)hb + 320000);   // 131,072 f
  unsigned short* Wc1T = (unsigned short*)((float*)Btw + 131072);  // 36,864 f
  unsigned short* Wc2T = (unsigned short*)((float*)Wc1T + 36864);  // 9,216 f
  float* R1 = (float*)Wc2T + 9216;                 // shared scratch region
  unsigned short* A1b = (unsigned short*)R1;       // 10.24M ushort (20.5MB)
  unsigned short* A2b = (unsigned short*)R1;       // aliases A1b (after hlayer)

  // fused prep: zero cur + all weight transposes (one dispatch)
  prep_kernel<<<CURB + WTBLK + W1BLK + W2BLK, 256, 0, stream>>>(
      drug_w, root1, basis1, root2, basis2, (int4*)cur, Btw, Wc1T, Wc2T);

  // CSR build
  scatter_kernel<<<(NE + 255) / 256, 256, 0, stream>>>(ei, cur, rec);

  // x = bf16(x_drug @ drug_w) — counted-vmcnt pipelined
  gemm0_mfma<<<NN / 16, 256, 0, stream>>>(x_drug, Btw, xb);

  // === MEASUREMENT PROBE: agg1e launched 3x (idempotent; identical A1b). ===
  // g1 = (total - 147.6)/2. Intentionally slower this round.
  agg1e_kernel<<<NN / 4, 256, 0, stream>>>(xb, cur, rec, comp1, A1b);
  agg1e_kernel<<<NN / 4, 256, 0, stream>>>(xb, cur, rec, comp1, A1b);
  agg1e_kernel<<<NN / 4, 256, 0, stream>>>(xb, cur, rec, comp1, A1b);
  hlayer_mfma<<<(NN + 31) / 32, 256, 0, stream>>>(xb, A1b, Wc1T, bias1, hb);

  // layer 2
  agg2e_kernel<<<NN / 4, 256, 0, stream>>>(hb, cur, rec, comp2, A2b);
  out_mfma<<<(NN + 31) / 32, 256, 0, stream>>>(hb, A2b, Wc2T, bias2, out);
}

// Round 20
// 151.360 us; speedup vs baseline: 1.4250x; 1.4250x over previous
//
#include <hip/hip_runtime.h>

#define NN 10000    // nodes
#define RR 100      // relations
#define EE 5000     // edges per relation
#define D0 2048
#define D1 128
#define D2 64
#define D3 20
#define NE (RR*EE)  // 500000 edges total
#define MAXD 128    // fixed CSR stride per node (true max total deg ~80)

using short8  = __attribute__((ext_vector_type(8))) short;
using float4e = __attribute__((ext_vector_type(4))) float;

typedef const __attribute__((address_space(1))) void g_void;
typedef __attribute__((address_space(3))) void l_void;

__device__ __forceinline__ unsigned short f2bf(float f) {
  unsigned int u = __float_as_uint(f);
  unsigned int r = u + 0x7fffu + ((u >> 16) & 1u);   // RNE
  return (unsigned short)(r >> 16);
}
__device__ __forceinline__ float bf2f(unsigned short u) {
  return __uint_as_float(((unsigned int)u) << 16);
}
__device__ __forceinline__ unsigned int pk2(float lo, float hi) {
  return ((unsigned int)f2bf(hi) << 16) | (unsigned int)f2bf(lo);
}

// ---------------------------------------------------------------------------
// prep: fused {zero cur, wtrans, wc1t, wc2t}
// ---------------------------------------------------------------------------
#define CURB 10             // 2,504 int4 zeros (cur)
#define WTBLK 1024          // 262,144 elems
#define W1BLK 288           // 73,728 elems
#define W2BLK 72            // 18,432 elems
__global__ __launch_bounds__(256) void prep_kernel(
    const float* __restrict__ W, const float* __restrict__ root1,
    const float* __restrict__ basis1, const float* __restrict__ root2,
    const float* __restrict__ basis2, int4* __restrict__ cur4,
    unsigned short* __restrict__ Btw, unsigned short* __restrict__ Wc1T,
    unsigned short* __restrict__ Wc2T) {
  const int b = blockIdx.x, tid = threadIdx.x;
  if (b < CURB) {
    int i = b * 256 + tid;
    if (i < 2504) cur4[i] = make_int4(0, 0, 0, 0);
  } else if (b < CURB + WTBLK) {
    int idx = (b - CURB) * 256 + tid;                 // 128*2048, exact
    int n = idx >> 11, k = idx & 2047;
    Btw[idx] = f2bf(W[(size_t)k * 128 + n]);
  } else if (b < CURB + WTBLK + W1BLK) {
    int idx = (b - CURB - WTBLK) * 256 + tid;         // 64*1152, exact
    int o = idx / 1152, j = idx - o * 1152;
    float v = (j < 128) ? root1[j * 64 + o] : basis1[(j - 128) * 64 + o];
    Wc1T[idx] = f2bf(v);
  } else {
    int idx = (b - CURB - WTBLK - W1BLK) * 256 + tid; // 32*576, exact
    int c = idx / 576, j = idx - c * 576;
    float v = 0.f;
    if (c < 20) v = (j < 64) ? root2[j * 20 + c] : basis2[(j - 64) * 20 + c];
    Wc2T[idx] = f2bf(v);
  }
}

// ---------------------------------------------------------------------------
// scatter: ONE random 4B store per edge (rec only).
// ---------------------------------------------------------------------------
__global__ void scatter_kernel(const int* __restrict__ ei,
                               int* __restrict__ cur, int* __restrict__ rec) {
  int gid = blockIdx.x * 256 + threadIdx.x;
  if (gid >= NE) return;
  int r = gid / EE, e = gid - r * EE;
  int s = ei[r * 2 * EE + e];
  int d = ei[r * 2 * EE + EE + e];
  int p = atomicAdd(&cur[d], 1);
  if (p < MAXD) rec[d * MAXD + p] = (r << 14) | s;
}

// ---------------------------------------------------------------------------
// gemm0 — counted-vmcnt pipeline (round-11 version): xb = bf16(A @ W).
// Tile M=16, N=128, BK=64 (32 steps). 625 blocks, 52KB LDS, 3/CU.
// ---------------------------------------------------------------------------
__global__ __launch_bounds__(256, 3) void gemm0_mfma(
    const float* __restrict__ A, const unsigned short* __restrict__ Btw,
    unsigned short* __restrict__ xb) {
  __shared__ __align__(16) unsigned short Asb[2][16 * 64];    // 2 x 2 KB
  __shared__ __align__(16) unsigned short Bsb[3][128 * 64];   // 3 x 16 KB
  const int tid = threadIdx.x;
  const int m0 = blockIdx.x * 16;
  const int wv = tid >> 6, lane = tid & 63;
  const int lrow = lane & 15, quad = lane >> 4;

  const int ar = tid >> 4, ag = tid & 15;
  const float* Ap = &A[(size_t)(m0 + ar) * D0 + ag * 4];
  const int aw = (ar * 128 + ((ag * 8) ^ ((ar & 7) << 4))) >> 1;  // ushort idx

  const int rowB = wv * 32 + (lane >> 3);
  const int gch  = (lane & 7) ^ (lane >> 3);
  const unsigned short* BgBase = &Btw[(size_t)rowB * D0 + gch * 8];
  const int ldsB = wv * 2048;   // ushort idx of this wave's 4KB region

  float4 a0, a1;

#define G0_LOADB(buf, c)                                                     \
  { _Pragma("unroll")                                                        \
    for (int i = 0; i < 4; i++) {                                            \
      __builtin_amdgcn_global_load_lds(                                      \
          (g_void*)(BgBase + (size_t)i * 8 * D0 + (c) * 64),                 \
          (l_void*)&Bsb[buf][ldsB + i * 512], 16, 0, 0);                     \
    } }

#define G0_LOADA(reg, c)  { reg = *(const float4*)(Ap + (c) * 64); }

#define G0_PACKA(reg, buf)                                              \
  { uint2 p0;                                                           \
    p0.x = pk2(reg.x, reg.y); p0.y = pk2(reg.z, reg.w);                 \
    *(uint2*)&Asb[buf][aw] = p0; }

#define G0_COMPUTE(abuf, bbuf)                                          \
  { const int aswz = (lrow & 7) << 4;                                   \
    _Pragma("unroll")                                                   \
    for (int kk = 0; kk < 2; kk++) {                                    \
      short8 af = *(const short8*)&Asb[abuf][(lrow * 128 + ((quad * 16 + kk * 64) ^ aswz)) >> 1]; \
      _Pragma("unroll")                                                 \
      for (int nt = 0; nt < 2; nt++) {                                  \
        const int brow = wv * 32 + nt * 16 + lrow;                      \
        short8 bfr = *(const short8*)&Bsb[bbuf][(brow * 128 + ((quad * 16 + kk * 64) ^ ((brow & 7) << 4))) >> 1]; \
        acc[nt] = __builtin_amdgcn_mfma_f32_16x16x32_bf16(af, bfr, acc[nt], 0, 0, 0); \
      }                                                                 \
    } }

  float4e acc[2];
#pragma unroll
  for (int i = 0; i < 2; i++) { acc[i][0]=0.f; acc[i][1]=0.f; acc[i][2]=0.f; acc[i][3]=0.f; }

  G0_LOADA(a0, 0);
  G0_LOADB(0, 0);
  G0_LOADB(1, 1);
  G0_PACKA(a0, 0);
  G0_LOADA(a1, 1);
  asm volatile("s_waitcnt vmcnt(5) lgkmcnt(0)\ns_barrier" ::: "memory");

#pragma unroll
  for (int c = 0; c < 32; c++) {
    if (c <= 29) {
      G0_LOADB((c + 2) % 3, c + 2);
      if ((c & 1) == 0) { G0_LOADA(a0, c + 2); }
      else              { G0_LOADA(a1, c + 2); }
      __builtin_amdgcn_sched_barrier(0);
    }
    G0_COMPUTE(c & 1, c % 3);
    if (c <= 30) {
      if (((c + 1) & 1) == 0) { G0_PACKA(a0, 0); }
      else                    { G0_PACKA(a1, 1); }
      asm volatile("s_waitcnt vmcnt(5) lgkmcnt(0)\ns_barrier" ::: "memory");
    }
  }

#pragma unroll
  for (int nt = 0; nt < 2; nt++) {
    const int col = wv * 32 + nt * 16 + lrow;
#pragma unroll
    for (int r = 0; r < 4; r++) {
      const int row = m0 + quad * 4 + r;
      xb[(size_t)row * D1 + col] = f2bf(acc[nt][r]);
    }
  }
}

// ---------------------------------------------------------------------------
// agg1e: A1b[n, b*128+i] = bf16( sum_{e->n} esc_e*comp1[r_e,b]*x[src_e,i] )
// Round-19 probe: 34us/launch — gather-latency bound (~13 serial batches of
// only 4 in-flight 256B xb gathers). Edge unroll deepened 4 -> 8 (2x
// memory-level parallelism per wave). FMA order stays idx-ascending.
// ---------------------------------------------------------------------------
__global__ __launch_bounds__(256) void agg1e_kernel(
    const unsigned short* __restrict__ xb, const int* __restrict__ cur,
    const int* __restrict__ rec, const float* __restrict__ comp,
    unsigned short* __restrict__ A1b) {
  __shared__ float s_comp[RR * 8];
  __shared__ float s_rcp[4][RR];
  const int tid = threadIdx.x;
  for (int i = tid; i < RR * 8; i += 256) s_comp[i] = comp[i];
  const int wv = tid >> 6, lane = tid & 63;
  const int n = blockIdx.x * 4 + wv;          // always < NN (grid exact)
  int* hist = (int*)&s_rcp[wv][0];
  for (int i = lane; i < RR; i += 64) hist[i] = 0;
  __syncthreads();
  int cnt = cur[n]; if (cnt > MAXD) cnt = MAXD;
  if (lane < cnt)      atomicAdd(&hist[rec[n * MAXD + lane] >> 14], 1);
  if (lane + 64 < cnt) atomicAdd(&hist[rec[n * MAXD + lane + 64] >> 14], 1);
  __syncthreads();
  for (int i = lane; i < RR; i += 64) {
    int h = hist[i];
    s_rcp[wv][i] = 1.0f / (float)h;
  }
  __syncthreads();

  float acc[8][2];
#pragma unroll
  for (int b = 0; b < 8; b++) { acc[b][0] = 0.f; acc[b][1] = 0.f; }
  const int beg = n * MAXD, end = beg + cnt;
  int idx = beg;
  for (; idx + 7 < end; idx += 8) {
    int rc[8]; float sc[8]; unsigned int xv[8];
#pragma unroll
    for (int u = 0; u < 8; u++) rc[u] = rec[idx + u];
#pragma unroll
    for (int u = 0; u < 8; u++) sc[u] = s_rcp[wv][rc[u] >> 14];
#pragma unroll
    for (int u = 0; u < 8; u++)
      xv[u] = *(const unsigned int*)&xb[(size_t)(rc[u] & 16383) * D1 + lane * 2];
#pragma unroll
    for (int u = 0; u < 8; u++) {
      const float* cb = &s_comp[(rc[u] >> 14) * 8];
      float x0 = __uint_as_float((xv[u] & 0xffffu) << 16);
      float x1 = __uint_as_float(xv[u] & 0xffff0000u);
#pragma unroll
      for (int b = 0; b < 8; b++) {
        float w = sc[u] * cb[b];
        acc[b][0] += w * x0;
        acc[b][1] += w * x1;
      }
    }
  }
  for (; idx + 3 < end; idx += 4) {
    int rc[4]; float sc[4]; unsigned int xv[4];
#pragma unroll
    for (int u = 0; u < 4; u++) rc[u] = rec[idx + u];
#pragma unroll
    for (int u = 0; u < 4; u++) sc[u] = s_rcp[wv][rc[u] >> 14];
#pragma unroll
    for (int u = 0; u < 4; u++)
      xv[u] = *(const unsigned int*)&xb[(size_t)(rc[u] & 16383) * D1 + lane * 2];
#pragma unroll
    for (int u = 0; u < 4; u++) {
      const float* cb = &s_comp[(rc[u] >> 14) * 8];
      float x0 = __uint_as_float((xv[u] & 0xffffu) << 16);
      float x1 = __uint_as_float(xv[u] & 0xffff0000u);
#pragma unroll
      for (int b = 0; b < 8; b++) {
        float w = sc[u] * cb[b];
        acc[b][0] += w * x0;
        acc[b][1] += w * x1;
      }
    }
  }
  for (; idx < end; idx++) {
    int rc = rec[idx];
    float sc = s_rcp[wv][rc >> 14];
    unsigned int xv = *(const unsigned int*)&xb[(size_t)(rc & 16383) * D1 + lane * 2];
    const float* cb = &s_comp[(rc >> 14) * 8];
    float x0 = __uint_as_float((xv & 0xffffu) << 16);
    float x1 = __uint_as_float(xv & 0xffff0000u);
#pragma unroll
    for (int b = 0; b < 8; b++) {
      float w = sc * cb[b];
      acc[b][0] += w * x0;
      acc[b][1] += w * x1;
    }
  }
#pragma unroll
  for (int b = 0; b < 8; b++) {
    ushort2 o; o.x = f2bf(acc[b][0]); o.y = f2bf(acc[b][1]);
    *(ushort2*)&A1b[(size_t)n * 1024 + b * 128 + lane * 2] = o;
  }
}

// ---------------------------------------------------------------------------
// agg2e: A2b[n, b*64+i] = bf16( sum_{e->n} esc_e*comp2[r_e,b]*h[src_e,i] )
// Same 8-deep edge unroll.
// ---------------------------------------------------------------------------
__global__ __launch_bounds__(256) void agg2e_kernel(
    const unsigned short* __restrict__ hb, const int* __restrict__ cur,
    const int* __restrict__ rec, const float* __restrict__ comp,
    unsigned short* __restrict__ A2b) {
  __shared__ float s_comp[RR * 8];
  __shared__ float s_rcp[4][RR];
  const int tid = threadIdx.x;
  for (int i = tid; i < RR * 8; i += 256) s_comp[i] = comp[i];
  const int wv = tid >> 6, lane = tid & 63;
  const int n = blockIdx.x * 4 + wv;          // always < NN
  int* hist = (int*)&s_rcp[wv][0];
  for (int i = lane; i < RR; i += 64) hist[i] = 0;
  __syncthreads();
  int cnt = cur[n]; if (cnt > MAXD) cnt = MAXD;
  if (lane < cnt)      atomicAdd(&hist[rec[n * MAXD + lane] >> 14], 1);
  if (lane + 64 < cnt) atomicAdd(&hist[rec[n * MAXD + lane + 64] >> 14], 1);
  __syncthreads();
  for (int i = lane; i < RR; i += 64) {
    int h = hist[i];
    s_rcp[wv][i] = 1.0f / (float)h;
  }
  __syncthreads();

  float acc[8];
#pragma unroll
  for (int b = 0; b < 8; b++) acc[b] = 0.f;
  const int beg = n * MAXD, end = beg + cnt;
  int idx = beg;
  for (; idx + 7 < end; idx += 8) {
    int rc[8]; float sc[8]; float hv[8];
#pragma unroll
    for (int u = 0; u < 8; u++) rc[u] = rec[idx + u];
#pragma unroll
    for (int u = 0; u < 8; u++) sc[u] = s_rcp[wv][rc[u] >> 14];
#pragma unroll
    for (int u = 0; u < 8; u++)
      hv[u] = bf2f(hb[(size_t)(rc[u] & 16383) * D2 + lane]);
#pragma unroll
    for (int u = 0; u < 8; u++) {
      const float* cb = &s_comp[(rc[u] >> 14) * 8];
#pragma unroll
      for (int b = 0; b < 8; b++) acc[b] += sc[u] * cb[b] * hv[u];
    }
  }
  for (; idx + 3 < end; idx += 4) {
    int rc[4]; float sc[4]; float hv[4];
#pragma unroll
    for (int u = 0; u < 4; u++) rc[u] = rec[idx + u];
#pragma unroll
    for (int u = 0; u < 4; u++) sc[u] = s_rcp[wv][rc[u] >> 14];
#pragma unroll
    for (int u = 0; u < 4; u++)
      hv[u] = bf2f(hb[(size_t)(rc[u] & 16383) * D2 + lane]);
#pragma unroll
    for (int u = 0; u < 4; u++) {
      const float* cb = &s_comp[(rc[u] >> 14) * 8];
#pragma unroll
      for (int b = 0; b < 8; b++) acc[b] += sc[u] * cb[b] * hv[u];
    }
  }
  for (; idx < end; idx++) {
    int rc = rec[idx];
    float sc = s_rcp[wv][rc >> 14];
    float hv = bf2f(hb[(size_t)(rc & 16383) * D2 + lane]);
    const float* cb = &s_comp[(rc >> 14) * 8];
#pragma unroll
    for (int b = 0; b < 8; b++) acc[b] += sc * cb[b] * hv;
  }
#pragma unroll
  for (int b = 0; b < 8; b++)
    A2b[(size_t)n * 512 + b * 64 + lane] = f2bf(acc[b]);
}

// ---------------------------------------------------------------------------
// hlayer: hb = bf16(relu([xb|A1b](K=1152) @ Wc1T + bias1))
// ---------------------------------------------------------------------------
__global__ __launch_bounds__(256) void hlayer_mfma(
    const unsigned short* __restrict__ xb, const unsigned short* __restrict__ A1b,
    const unsigned short* __restrict__ Wt, const float* __restrict__ bias1,
    unsigned short* __restrict__ hb) {
  __shared__ __align__(16) unsigned short Asb[2][32 * 64];   // 8 KB
  __shared__ __align__(16) unsigned short Bsb[2][64 * 64];   // 16 KB
  const int tid = threadIdx.x;
  const int m0 = blockIdx.x * 32;
  const int wv = tid >> 6, lane = tid & 63;
  const int lrow = lane & 15, quad = lane >> 4;
  const int mt = wv >> 1, nb = wv & 1;    // wave: 16 rows x 32 cols

  const int ar = tid >> 3, ac = tid & 7;
  int gr = m0 + ar; if (gr >= NN) gr = NN - 1;
  const unsigned short* Ax = &xb[(size_t)gr * D1 + ac * 8];     // steps 0-1
  const unsigned short* Aa = &A1b[(size_t)gr * 1024 + ac * 8];  // steps 2-17
  const int asw = (ar & 7) << 4;
  const int aw = (ar * 128 + ((ac * 16) ^ asw)) >> 1;

  const int br = tid >> 2, bq = tid & 3;
  const unsigned short* Bp = &Wt[(size_t)br * 1152 + bq * 16];
  const int bsw = (br & 7) << 4;
  const int bw0 = (br * 128 + ((bq * 32) ^ bsw)) >> 1;
  const int bw1 = (br * 128 + ((bq * 32 + 16) ^ bsw)) >> 1;

  uint4 ra, rb0, rb1;

#define H_LOADG(c)                                                       \
  { int kb = (c) * 64;                                                   \
    ra  = (kb < 128) ? *(const uint4*)(Ax + kb)                          \
                     : *(const uint4*)(Aa + (kb - 128));                 \
    rb0 = *(const uint4*)(Bp + kb);                                      \
    rb1 = *(const uint4*)(Bp + kb + 8); }

#define H_STOREL(buf)                                                    \
  { *(uint4*)&Asb[buf][aw]  = ra;                                        \
    *(uint4*)&Bsb[buf][bw0] = rb0;                                       \
    *(uint4*)&Bsb[buf][bw1] = rb1; }

#define H_COMPUTE(buf)                                                   \
  { const int arow = mt * 16 + lrow;                                     \
    const int aswz = (arow & 7) << 4;                                    \
    _Pragma("unroll")                                                    \
    for (int kk = 0; kk < 2; kk++) {                                     \
      short8 af = *(const short8*)&Asb[buf][(arow * 128 + ((quad * 16 + kk * 64) ^ aswz)) >> 1]; \
      _Pragma("unroll")                                                  \
      for (int nt = 0; nt < 2; nt++) {                                   \
        const int brow = nb * 32 + nt * 16 + lrow;                       \
        short8 bfr = *(const short8*)&Bsb[buf][(brow * 128 + ((quad * 16 + kk * 64) ^ ((brow & 7) << 4))) >> 1]; \
        acc[nt] = __builtin_amdgcn_mfma_f32_16x16x32_bf16(af, bfr, acc[nt], 0, 0, 0); \
      }                                                                  \
    } }

  float4e acc[2];
#pragma unroll
  for (int i = 0; i < 2; i++) { acc[i][0]=0.f; acc[i][1]=0.f; acc[i][2]=0.f; acc[i][3]=0.f; }

  H_LOADG(0);
  H_STOREL(0);
  __syncthreads();

#pragma unroll
  for (int c = 0; c < 18; c++) {
    if (c < 17) {
      H_LOADG(c + 1);
      __builtin_amdgcn_sched_barrier(0);   // pin prefetch before compute
    }
    H_COMPUTE(c & 1);
    if (c < 17) H_STOREL((c + 1) & 1);
    __syncthreads();
  }

#pragma unroll
  for (int nt = 0; nt < 2; nt++) {
    int col = nb * 32 + nt * 16 + lrow;
    float bv = bias1[col];
#pragma unroll
    for (int r = 0; r < 4; r++) {
      int row = m0 + mt * 16 + quad * 4 + r;
      if (row < NN)
        hb[(size_t)row * D2 + col] = f2bf(fmaxf(acc[nt][r] + bv, 0.f));
    }
  }
}

// ---------------------------------------------------------------------------
// out: out = [hb|A2b](K=576) @ Wc2T + bias2
// ---------------------------------------------------------------------------
__global__ __launch_bounds__(256) void out_mfma(
    const unsigned short* __restrict__ hb, const unsigned short* __restrict__ A2b,
    const unsigned short* __restrict__ Wt, const float* __restrict__ bias2,
    float* __restrict__ out) {
  __shared__ __align__(16) unsigned short Asb[2][32 * 64];   // 8 KB
  __shared__ __align__(16) unsigned short Bsb[2][32 * 64];   // 8 KB
  const int tid = threadIdx.x;
  const int m0 = blockIdx.x * 32;
  const int wv = tid >> 6, lane = tid & 63;
  const int lrow = lane & 15, quad = lane >> 4;
  const int mt = wv >> 1, ntn = wv & 1;   // wave: 16 rows x 16 cols

  const int ar = tid >> 3, ac = tid & 7;
  int gr = m0 + ar; if (gr >= NN) gr = NN - 1;
  const unsigned short* Ah = &hb[(size_t)gr * D2 + ac * 8];     // step 0
  const unsigned short* Aa = &A2b[(size_t)gr * 512 + ac * 8];   // steps 1-8
  const unsigned short* Bp = &Wt[(size_t)ar * 576 + ac * 8];
  const int asw = (ar & 7) << 4;
  const int aw = (ar * 128 + ((ac * 16) ^ asw)) >> 1;

  uint4 ra, rb;

#define O_LOADG(c)                                                       \
  { int kb = (c) * 64;                                                   \
    ra = (kb < 64) ? *(const uint4*)(Ah)                                 \
                   : *(const uint4*)(Aa + (kb - 64));                    \
    rb = *(const uint4*)(Bp + kb); }

#define O_STOREL(buf)                                                    \
  { *(uint4*)&Asb[buf][aw] = ra;                                         \
    *(uint4*)&Bsb[buf][aw] = rb; }

#define O_COMPUTE(buf)                                                   \
  { const int arow = mt * 16 + lrow;                                     \
    const int aswz = (arow & 7) << 4;                                    \
    const int brow = ntn * 16 + lrow;                                    \
    const int bswz = (brow & 7) << 4;                                    \
    _Pragma("unroll")                                                    \
    for (int kk = 0; kk < 2; kk++) {                                     \
      short8 af = *(const short8*)&Asb[buf][(arow * 128 + ((quad * 16 + kk * 64) ^ aswz)) >> 1]; \
      short8 bfr = *(const short8*)&Bsb[buf][(brow * 128 + ((quad * 16 + kk * 64) ^ bswz)) >> 1]; \
      acc = __builtin_amdgcn_mfma_f32_16x16x32_bf16(af, bfr, acc, 0, 0, 0); \
    } }

  float4e acc;
  acc[0]=0.f; acc[1]=0.f; acc[2]=0.f; acc[3]=0.f;

  O_LOADG(0);
  O_STOREL(0);
  __syncthreads();

#pragma unroll
  for (int c = 0; c < 9; c++) {
    if (c < 8) {
      O_LOADG(c + 1);
      __builtin_amdgcn_sched_barrier(0);   // pin prefetch before compute
    }
    O_COMPUTE(c & 1);
    if (c < 8) O_STOREL((c + 1) & 1);
    __syncthreads();
  }

  int col = ntn * 16 + lrow;
  if (col < D3) {
    float bv = bias2[col];
#pragma unroll
    for (int r = 0; r < 4; r++) {
      int row = m0 + mt * 16 + quad * 4 + r;
      if (row < NN)
        out[(size_t)row * D3 + col] = acc[r] + bv;
    }
  }
}

// ---------------------------------------------------------------------------
extern "C" void kernel_launch(void* const* d_in, const int* in_sizes, int n_in,
                              void* d_out, int out_size, void* d_ws,
                              size_t ws_size, hipStream_t stream) {
  const float* x_drug = (const float*)d_in[0];
  const float* drug_w = (const float*)d_in[1];
  const int*   ei     = (const int*)d_in[2];
  const float* basis1 = (const float*)d_in[3];
  const float* comp1  = (const float*)d_in[4];
  const float* root1  = (const float*)d_in[5];
  const float* bias1  = (const float*)d_in[6];
  const float* basis2 = (const float*)d_in[7];
  const float* comp2  = (const float*)d_in[8];
  const float* root2  = (const float*)d_in[9];
  const float* bias2  = (const float*)d_in[10];
  float* out = (float*)d_out;

  float* ws = (float*)d_ws;
  int*   cur  = (int*)ws;                          // 10,016
  int*   rec  = cur + 10016;                       // 1,280,000 (NN*MAXD)
  unsigned short* xb   = (unsigned short*)(rec + NN * MAXD);       // 640,000 f
  unsigned short* hb   = (unsigned short*)((float*)xb + 640000);   // 320,000 f
  unsigned short* Btw  = (unsigned short*)((float*)hb + 320000);   // 131,072 f
  unsigned short* Wc1T = (unsigned short*)((float*)Btw + 131072);  // 36,864 f
  unsigned short* Wc2T = (unsigned short*)((float*)Wc1T + 36864);  // 9,216 f
  float* R1 = (float*)Wc2T + 9216;                 // shared scratch region
  unsigned short* A1b = (unsigned short*)R1;       // 10.24M ushort (20.5MB)
  unsigned short* A2b = (unsigned short*)R1;       // aliases A1b (after hlayer)

  // fused prep: zero cur + all weight transposes (one dispatch)
  prep_kernel<<<CURB + WTBLK + W1BLK + W2BLK, 256, 0, stream>>>(
      drug_w, root1, basis1, root2, basis2, (int4*)cur, Btw, Wc1T, Wc2T);

  // CSR build
  scatter_kernel<<<(NE + 255) / 256, 256, 0, stream>>>(ei, cur, rec);

  // x = bf16(x_drug @ drug_w) — counted-vmcnt pipelined
  gemm0_mfma<<<NN / 16, 256, 0, stream>>>(x_drug, Btw, xb);

  // layer 1 (agg1e: 8-deep gather unroll)
  agg1e_kernel<<<NN / 4, 256, 0, stream>>>(xb, cur, rec, comp1, A1b);
  hlayer_mfma<<<(NN + 31) / 32, 256, 0, stream>>>(xb, A1b, Wc1T, bias1, hb);

  // layer 2 (agg2e: 8-deep gather unroll)
  agg2e_kernel<<<NN / 4, 256, 0, stream>>>(hb, cur, rec, comp2, A2b);
  out_mfma<<<(NN + 31) / 32, 256, 0, stream>>>(hb, A2b, Wc2T, bias2, out);
}

// Round 21
// 149.011 us; speedup vs baseline: 1.4475x; 1.0158x over previous
//
#include <hip/hip_runtime.h>

#define NN 10000    // nodes
#define RR 100      // relations
#define EE 5000     // edges per relation
#define D0 2048
#define D1 128
#define D2 64
#define D3 20
#define NE (RR*EE)  // 500000 edges total
#define MAXD 128    // fixed CSR stride per node (true max total deg ~80)

using short8  = __attribute__((ext_vector_type(8))) short;
using float4e = __attribute__((ext_vector_type(4))) float;

typedef const __attribute__((address_space(1))) void g_void;
typedef __attribute__((address_space(3))) void l_void;

__device__ __forceinline__ unsigned short f2bf(float f) {
  unsigned int u = __float_as_uint(f);
  unsigned int r = u + 0x7fffu + ((u >> 16) & 1u);   // RNE
  return (unsigned short)(r >> 16);
}
__device__ __forceinline__ float bf2f(unsigned short u) {
  return __uint_as_float(((unsigned int)u) << 16);
}
__device__ __forceinline__ unsigned int pk2(float lo, float hi) {
  return ((unsigned int)f2bf(hi) << 16) | (unsigned int)f2bf(lo);
}

// ---------------------------------------------------------------------------
// prep: fused {zero cur, wtrans, wc1t, wc2t}
// ---------------------------------------------------------------------------
#define CURB 10             // 2,504 int4 zeros (cur)
#define WTBLK 1024          // 262,144 elems
#define W1BLK 288           // 73,728 elems
#define W2BLK 72            // 18,432 elems
__global__ __launch_bounds__(256) void prep_kernel(
    const float* __restrict__ W, const float* __restrict__ root1,
    const float* __restrict__ basis1, const float* __restrict__ root2,
    const float* __restrict__ basis2, int4* __restrict__ cur4,
    unsigned short* __restrict__ Btw, unsigned short* __restrict__ Wc1T,
    unsigned short* __restrict__ Wc2T) {
  const int b = blockIdx.x, tid = threadIdx.x;
  if (b < CURB) {
    int i = b * 256 + tid;
    if (i < 2504) cur4[i] = make_int4(0, 0, 0, 0);
  } else if (b < CURB + WTBLK) {
    int idx = (b - CURB) * 256 + tid;                 // 128*2048, exact
    int n = idx >> 11, k = idx & 2047;
    Btw[idx] = f2bf(W[(size_t)k * 128 + n]);
  } else if (b < CURB + WTBLK + W1BLK) {
    int idx = (b - CURB - WTBLK) * 256 + tid;         // 64*1152, exact
    int o = idx / 1152, j = idx - o * 1152;
    float v = (j < 128) ? root1[j * 64 + o] : basis1[(j - 128) * 64 + o];
    Wc1T[idx] = f2bf(v);
  } else {
    int idx = (b - CURB - WTBLK - W1BLK) * 256 + tid; // 32*576, exact
    int c = idx / 576, j = idx - c * 576;
    float v = 0.f;
    if (c < 20) v = (j < 64) ? root2[j * 20 + c] : basis2[(j - 64) * 20 + c];
    Wc2T[idx] = f2bf(v);
  }
}

// ---------------------------------------------------------------------------
// scatter: ONE random 4B store per edge (rec only).
// ---------------------------------------------------------------------------
__global__ void scatter_kernel(const int* __restrict__ ei,
                               int* __restrict__ cur, int* __restrict__ rec) {
  int gid = blockIdx.x * 256 + threadIdx.x;
  if (gid >= NE) return;
  int r = gid / EE, e = gid - r * EE;
  int s = ei[r * 2 * EE + e];
  int d = ei[r * 2 * EE + EE + e];
  int p = atomicAdd(&cur[d], 1);
  if (p < MAXD) rec[d * MAXD + p] = (r << 14) | s;
}

// ---------------------------------------------------------------------------
// gemm0 — counted-vmcnt pipeline (round-11 version): xb = bf16(A @ W).
// Tile M=16, N=128, BK=64 (32 steps). 625 blocks, 52KB LDS, 3/CU.
// ---------------------------------------------------------------------------
__global__ __launch_bounds__(256, 3) void gemm0_mfma(
    const float* __restrict__ A, const unsigned short* __restrict__ Btw,
    unsigned short* __restrict__ xb) {
  __shared__ __align__(16) unsigned short Asb[2][16 * 64];    // 2 x 2 KB
  __shared__ __align__(16) unsigned short Bsb[3][128 * 64];   // 3 x 16 KB
  const int tid = threadIdx.x;
  const int m0 = blockIdx.x * 16;
  const int wv = tid >> 6, lane = tid & 63;
  const int lrow = lane & 15, quad = lane >> 4;

  const int ar = tid >> 4, ag = tid & 15;
  const float* Ap = &A[(size_t)(m0 + ar) * D0 + ag * 4];
  const int aw = (ar * 128 + ((ag * 8) ^ ((ar & 7) << 4))) >> 1;  // ushort idx

  const int rowB = wv * 32 + (lane >> 3);
  const int gch  = (lane & 7) ^ (lane >> 3);
  const unsigned short* BgBase = &Btw[(size_t)rowB * D0 + gch * 8];
  const int ldsB = wv * 2048;   // ushort idx of this wave's 4KB region

  float4 a0, a1;

#define G0_LOADB(buf, c)                                                     \
  { _Pragma("unroll")                                                        \
    for (int i = 0; i < 4; i++) {                                            \
      __builtin_amdgcn_global_load_lds(                                      \
          (g_void*)(BgBase + (size_t)i * 8 * D0 + (c) * 64),                 \
          (l_void*)&Bsb[buf][ldsB + i * 512], 16, 0, 0);                     \
    } }

#define G0_LOADA(reg, c)  { reg = *(const float4*)(Ap + (c) * 64); }

#define G0_PACKA(reg, buf)                                              \
  { uint2 p0;                                                           \
    p0.x = pk2(reg.x, reg.y); p0.y = pk2(reg.z, reg.w);                 \
    *(uint2*)&Asb[buf][aw] = p0; }

#define G0_COMPUTE(abuf, bbuf)                                          \
  { const int aswz = (lrow & 7) << 4;                                   \
    _Pragma("unroll")                                                   \
    for (int kk = 0; kk < 2; kk++) {                                    \
      short8 af = *(const short8*)&Asb[abuf][(lrow * 128 + ((quad * 16 + kk * 64) ^ aswz)) >> 1]; \
      _Pragma("unroll")                                                 \
      for (int nt = 0; nt < 2; nt++) {                                  \
        const int brow = wv * 32 + nt * 16 + lrow;                      \
        short8 bfr = *(const short8*)&Bsb[bbuf][(brow * 128 + ((quad * 16 + kk * 64) ^ ((brow & 7) << 4))) >> 1]; \
        acc[nt] = __builtin_amdgcn_mfma_f32_16x16x32_bf16(af, bfr, acc[nt], 0, 0, 0); \
      }                                                                 \
    } }

  float4e acc[2];
#pragma unroll
  for (int i = 0; i < 2; i++) { acc[i][0]=0.f; acc[i][1]=0.f; acc[i][2]=0.f; acc[i][3]=0.f; }

  G0_LOADA(a0, 0);
  G0_LOADB(0, 0);
  G0_LOADB(1, 1);
  G0_PACKA(a0, 0);
  G0_LOADA(a1, 1);
  asm volatile("s_waitcnt vmcnt(5) lgkmcnt(0)\ns_barrier" ::: "memory");

#pragma unroll
  for (int c = 0; c < 32; c++) {
    if (c <= 29) {
      G0_LOADB((c + 2) % 3, c + 2);
      if ((c & 1) == 0) { G0_LOADA(a0, c + 2); }
      else              { G0_LOADA(a1, c + 2); }
      __builtin_amdgcn_sched_barrier(0);
    }
    G0_COMPUTE(c & 1, c % 3);
    if (c <= 30) {
      if (((c + 1) & 1) == 0) { G0_PACKA(a0, 0); }
      else                    { G0_PACKA(a1, 1); }
      asm volatile("s_waitcnt vmcnt(5) lgkmcnt(0)\ns_barrier" ::: "memory");
    }
  }

#pragma unroll
  for (int nt = 0; nt < 2; nt++) {
    const int col = wv * 32 + nt * 16 + lrow;
#pragma unroll
    for (int r = 0; r < 4; r++) {
      const int row = m0 + quad * 4 + r;
      xb[(size_t)row * D1 + col] = f2bf(acc[nt][r]);
    }
  }
}

// ---------------------------------------------------------------------------
// agg1e: A1b[n, b*128+i] = bf16( sum_{e->n} esc_e*comp1[r_e,b]*x[src_e,i] )
// 4-deep unroll (8-deep regressed: +3.8us from register pressure at full
// wave residency). Gathers issued BEFORE the sc LDS lookups.
// ---------------------------------------------------------------------------
__global__ __launch_bounds__(256) void agg1e_kernel(
    const unsigned short* __restrict__ xb, const int* __restrict__ cur,
    const int* __restrict__ rec, const float* __restrict__ comp,
    unsigned short* __restrict__ A1b) {
  __shared__ float s_comp[RR * 8];
  __shared__ float s_rcp[4][RR];
  const int tid = threadIdx.x;
  for (int i = tid; i < RR * 8; i += 256) s_comp[i] = comp[i];
  const int wv = tid >> 6, lane = tid & 63;
  const int n = blockIdx.x * 4 + wv;          // always < NN (grid exact)
  int* hist = (int*)&s_rcp[wv][0];
  for (int i = lane; i < RR; i += 64) hist[i] = 0;
  __syncthreads();
  int cnt = cur[n]; if (cnt > MAXD) cnt = MAXD;
  if (lane < cnt)      atomicAdd(&hist[rec[n * MAXD + lane] >> 14], 1);
  if (lane + 64 < cnt) atomicAdd(&hist[rec[n * MAXD + lane + 64] >> 14], 1);
  __syncthreads();
  for (int i = lane; i < RR; i += 64) {
    int h = hist[i];
    s_rcp[wv][i] = 1.0f / (float)h;
  }
  __syncthreads();

  float acc[8][2];
#pragma unroll
  for (int b = 0; b < 8; b++) { acc[b][0] = 0.f; acc[b][1] = 0.f; }
  const int beg = n * MAXD, end = beg + cnt;
  int idx = beg;
  for (; idx + 3 < end; idx += 4) {
    int rc[4]; float sc[4]; unsigned int xv[4];
#pragma unroll
    for (int u = 0; u < 4; u++) rc[u] = rec[idx + u];
#pragma unroll
    for (int u = 0; u < 4; u++)
      xv[u] = *(const unsigned int*)&xb[(size_t)(rc[u] & 16383) * D1 + lane * 2];
#pragma unroll
    for (int u = 0; u < 4; u++) sc[u] = s_rcp[wv][rc[u] >> 14];
#pragma unroll
    for (int u = 0; u < 4; u++) {
      const float* cb = &s_comp[(rc[u] >> 14) * 8];
      float x0 = __uint_as_float((xv[u] & 0xffffu) << 16);
      float x1 = __uint_as_float(xv[u] & 0xffff0000u);
#pragma unroll
      for (int b = 0; b < 8; b++) {
        float w = sc[u] * cb[b];
        acc[b][0] += w * x0;
        acc[b][1] += w * x1;
      }
    }
  }
  for (; idx < end; idx++) {
    int rc = rec[idx];
    unsigned int xv = *(const unsigned int*)&xb[(size_t)(rc & 16383) * D1 + lane * 2];
    float sc = s_rcp[wv][rc >> 14];
    const float* cb = &s_comp[(rc >> 14) * 8];
    float x0 = __uint_as_float((xv & 0xffffu) << 16);
    float x1 = __uint_as_float(xv & 0xffff0000u);
#pragma unroll
    for (int b = 0; b < 8; b++) {
      float w = sc * cb[b];
      acc[b][0] += w * x0;
      acc[b][1] += w * x1;
    }
  }
#pragma unroll
  for (int b = 0; b < 8; b++) {
    ushort2 o; o.x = f2bf(acc[b][0]); o.y = f2bf(acc[b][1]);
    *(ushort2*)&A1b[(size_t)n * 1024 + b * 128 + lane * 2] = o;
  }
}

// ---------------------------------------------------------------------------
// agg2e: A2b[n, b*64+i] = bf16( sum_{e->n} esc_e*comp2[r_e,b]*h[src_e,i] )
// ---------------------------------------------------------------------------
__global__ __launch_bounds__(256) void agg2e_kernel(
    const unsigned short* __restrict__ hb, const int* __restrict__ cur,
    const int* __restrict__ rec, const float* __restrict__ comp,
    unsigned short* __restrict__ A2b) {
  __shared__ float s_comp[RR * 8];
  __shared__ float s_rcp[4][RR];
  const int tid = threadIdx.x;
  for (int i = tid; i < RR * 8; i += 256) s_comp[i] = comp[i];
  const int wv = tid >> 6, lane = tid & 63;
  const int n = blockIdx.x * 4 + wv;          // always < NN
  int* hist = (int*)&s_rcp[wv][0];
  for (int i = lane; i < RR; i += 64) hist[i] = 0;
  __syncthreads();
  int cnt = cur[n]; if (cnt > MAXD) cnt = MAXD;
  if (lane < cnt)      atomicAdd(&hist[rec[n * MAXD + lane] >> 14], 1);
  if (lane + 64 < cnt) atomicAdd(&hist[rec[n * MAXD + lane + 64] >> 14], 1);
  __syncthreads();
  for (int i = lane; i < RR; i += 64) {
    int h = hist[i];
    s_rcp[wv][i] = 1.0f / (float)h;
  }
  __syncthreads();

  float acc[8];
#pragma unroll
  for (int b = 0; b < 8; b++) acc[b] = 0.f;
  const int beg = n * MAXD, end = beg + cnt;
  int idx = beg;
  for (; idx + 3 < end; idx += 4) {
    int rc[4]; float sc[4]; float hv[4];
#pragma unroll
    for (int u = 0; u < 4; u++) rc[u] = rec[idx + u];
#pragma unroll
    for (int u = 0; u < 4; u++)
      hv[u] = bf2f(hb[(size_t)(rc[u] & 16383) * D2 + lane]);
#pragma unroll
    for (int u = 0; u < 4; u++) sc[u] = s_rcp[wv][rc[u] >> 14];
#pragma unroll
    for (int u = 0; u < 4; u++) {
      const float* cb = &s_comp[(rc[u] >> 14) * 8];
#pragma unroll
      for (int b = 0; b < 8; b++) acc[b] += sc[u] * cb[b] * hv[u];
    }
  }
  for (; idx < end; idx++) {
    int rc = rec[idx];
    float hv = bf2f(hb[(size_t)(rc & 16383) * D2 + lane]);
    float sc = s_rcp[wv][rc >> 14];
    const float* cb = &s_comp[(rc >> 14) * 8];
#pragma unroll
    for (int b = 0; b < 8; b++) acc[b] += sc * cb[b] * hv;
  }
#pragma unroll
  for (int b = 0; b < 8; b++)
    A2b[(size_t)n * 512 + b * 64 + lane] = f2bf(acc[b]);
}

// ---------------------------------------------------------------------------
// hlayer: hb = bf16(relu([xb|A1b](K=1152) @ Wc1T + bias1))
// ---------------------------------------------------------------------------
__global__ __launch_bounds__(256) void hlayer_mfma(
    const unsigned short* __restrict__ xb, const unsigned short* __restrict__ A1b,
    const unsigned short* __restrict__ Wt, const float* __restrict__ bias1,
    unsigned short* __restrict__ hb) {
  __shared__ __align__(16) unsigned short Asb[2][32 * 64];   // 8 KB
  __shared__ __align__(16) unsigned short Bsb[2][64 * 64];   // 16 KB
  const int tid = threadIdx.x;
  const int m0 = blockIdx.x * 32;
  const int wv = tid >> 6, lane = tid & 63;
  const int lrow = lane & 15, quad = lane >> 4;
  const int mt = wv >> 1, nb = wv & 1;    // wave: 16 rows x 32 cols

  const int ar = tid >> 3, ac = tid & 7;
  int gr = m0 + ar; if (gr >= NN) gr = NN - 1;
  const unsigned short* Ax = &xb[(size_t)gr * D1 + ac * 8];     // steps 0-1
  const unsigned short* Aa = &A1b[(size_t)gr * 1024 + ac * 8];  // steps 2-17
  const int asw = (ar & 7) << 4;
  const int aw = (ar * 128 + ((ac * 16) ^ asw)) >> 1;

  const int br = tid >> 2, bq = tid & 3;
  const unsigned short* Bp = &Wt[(size_t)br * 1152 + bq * 16];
  const int bsw = (br & 7) << 4;
  const int bw0 = (br * 128 + ((bq * 32) ^ bsw)) >> 1;
  const int bw1 = (br * 128 + ((bq * 32 + 16) ^ bsw)) >> 1;

  uint4 ra, rb0, rb1;

#define H_LOADG(c)                                                       \
  { int kb = (c) * 64;                                                   \
    ra  = (kb < 128) ? *(const uint4*)(Ax + kb)                          \
                     : *(const uint4*)(Aa + (kb - 128));                 \
    rb0 = *(const uint4*)(Bp + kb);                                      \
    rb1 = *(const uint4*)(Bp + kb + 8); }

#define H_STOREL(buf)                                                    \
  { *(uint4*)&Asb[buf][aw]  = ra;                                        \
    *(uint4*)&Bsb[buf][bw0] = rb0;                                       \
    *(uint4*)&Bsb[buf][bw1] = rb1; }

#define H_COMPUTE(buf)                                                   \
  { const int arow = mt * 16 + lrow;                                     \
    const int aswz = (arow & 7) << 4;                                    \
    _Pragma("unroll")                                                    \
    for (int kk = 0; kk < 2; kk++) {                                     \
      short8 af = *(const short8*)&Asb[buf][(arow * 128 + ((quad * 16 + kk * 64) ^ aswz)) >> 1]; \
      _Pragma("unroll")                                                  \
      for (int nt = 0; nt < 2; nt++) {                                   \
        const int brow = nb * 32 + nt * 16 + lrow;                       \
        short8 bfr = *(const short8*)&Bsb[buf][(brow * 128 + ((quad * 16 + kk * 64) ^ ((brow & 7) << 4))) >> 1]; \
        acc[nt] = __builtin_amdgcn_mfma_f32_16x16x32_bf16(af, bfr, acc[nt], 0, 0, 0); \
      }                                                                  \
    } }

  float4e acc[2];
#pragma unroll
  for (int i = 0; i < 2; i++) { acc[i][0]=0.f; acc[i][1]=0.f; acc[i][2]=0.f; acc[i][3]=0.f; }

  H_LOADG(0);
  H_STOREL(0);
  __syncthreads();

#pragma unroll
  for (int c = 0; c < 18; c++) {
    if (c < 17) {
      H_LOADG(c + 1);
      __builtin_amdgcn_sched_barrier(0);   // pin prefetch before compute
    }
    H_COMPUTE(c & 1);
    if (c < 17) H_STOREL((c + 1) & 1);
    __syncthreads();
  }

#pragma unroll
  for (int nt = 0; nt < 2; nt++) {
    int col = nb * 32 + nt * 16 + lrow;
    float bv = bias1[col];
#pragma unroll
    for (int r = 0; r < 4; r++) {
      int row = m0 + mt * 16 + quad * 4 + r;
      if (row < NN)
        hb[(size_t)row * D2 + col] = f2bf(fmaxf(acc[nt][r] + bv, 0.f));
    }
  }
}

// ---------------------------------------------------------------------------
// out: out = [hb|A2b](K=576) @ Wc2T + bias2
// ---------------------------------------------------------------------------
__global__ __launch_bounds__(256) void out_mfma(
    const unsigned short* __restrict__ hb, const unsigned short* __restrict__ A2b,
    const unsigned short* __restrict__ Wt, const float* __restrict__ bias2,
    float* __restrict__ out) {
  __shared__ __align__(16) unsigned short Asb[2][32 * 64];   // 8 KB
  __shared__ __align__(16) unsigned short Bsb[2][32 * 64];   // 8 KB
  const int tid = threadIdx.x;
  const int m0 = blockIdx.x * 32;
  const int wv = tid >> 6, lane = tid & 63;
  const int lrow = lane & 15, quad = lane >> 4;
  const int mt = wv >> 1, ntn = wv & 1;   // wave: 16 rows x 16 cols

  const int ar = tid >> 3, ac = tid & 7;
  int gr = m0 + ar; if (gr >= NN) gr = NN - 1;
  const unsigned short* Ah = &hb[(size_t)gr * D2 + ac * 8];     // step 0
  const unsigned short* Aa = &A2b[(size_t)gr * 512 + ac * 8];   // steps 1-8
  const unsigned short* Bp = &Wt[(size_t)ar * 576 + ac * 8];
  const int asw = (ar & 7) << 4;
  const int aw = (ar * 128 + ((ac * 16) ^ asw)) >> 1;

  uint4 ra, rb;

#define O_LOADG(c)                                                       \
  { int kb = (c) * 64;                                                   \
    ra = (kb < 64) ? *(const uint4*)(Ah)                                 \
                   : *(const uint4*)(Aa + (kb - 64));                    \
    rb = *(const uint4*)(Bp + kb); }

#define O_STOREL(buf)                                                    \
  { *(uint4*)&Asb[buf][aw] = ra;                                         \
    *(uint4*)&Bsb[buf][aw] = rb; }

#define O_COMPUTE(buf)                                                   \
  { const int arow = mt * 16 + lrow;                                     \
    const int aswz = (arow & 7) << 4;                                    \
    const int brow = ntn * 16 + lrow;                                    \
    const int bswz = (brow & 7) << 4;                                    \
    _Pragma("unroll")                                                    \
    for (int kk = 0; kk < 2; kk++) {                                     \
      short8 af = *(const short8*)&Asb[buf][(arow * 128 + ((quad * 16 + kk * 64) ^ aswz)) >> 1]; \
      short8 bfr = *(const short8*)&Bsb[buf][(brow * 128 + ((quad * 16 + kk * 64) ^ bswz)) >> 1]; \
      acc = __builtin_amdgcn_mfma_f32_16x16x32_bf16(af, bfr, acc, 0, 0, 0); \
    } }

  float4e acc;
  acc[0]=0.f; acc[1]=0.f; acc[2]=0.f; acc[3]=0.f;

  O_LOADG(0);
  O_STOREL(0);
  __syncthreads();

#pragma unroll
  for (int c = 0; c < 9; c++) {
    if (c < 8) {
      O_LOADG(c + 1);
      __builtin_amdgcn_sched_barrier(0);   // pin prefetch before compute
    }
    O_COMPUTE(c & 1);
    if (c < 8) O_STOREL((c + 1) & 1);
    __syncthreads();
  }

  int col = ntn * 16 + lrow;
  if (col < D3) {
    float bv = bias2[col];
#pragma unroll
    for (int r = 0; r < 4; r++) {
      int row = m0 + mt * 16 + quad * 4 + r;
      if (row < NN)
        out[(size_t)row * D3 + col] = acc[r] + bv;
    }
  }
}

// ---------------------------------------------------------------------------
extern "C" void kernel_launch(void* const* d_in, const int* in_sizes, int n_in,
                              void* d_out, int out_size, void* d_ws,
                              size_t ws_size, hipStream_t stream) {
  const float* x_drug = (const float*)d_in[0];
  const float* drug_w = (const float*)d_in[1];
  const int*   ei     = (const int*)d_in[2];
  const float* basis1 = (const float*)d_in[3];
  const float* comp1  = (const float*)d_in[4];
  const float* root1  = (const float*)d_in[5];
  const float* bias1  = (const float*)d_in[6];
  const float* basis2 = (const float*)d_in[7];
  const float* comp2  = (const float*)d_in[8];
  const float* root2  = (const float*)d_in[9];
  const float* bias2  = (const float*)d_in[10];
  float* out = (float*)d_out;

  float* ws = (float*)d_ws;
  int*   cur  = (int*)ws;                          // 10,016
  int*   rec  = cur + 10016;                       // 1,280,000 (NN*MAXD)
  unsigned short* xb   = (unsigned short*)(rec + NN * MAXD);       // 640,000 f
  unsigned short* hb   = (unsigned short*)((float*)xb + 640000);   // 320,000 f
  unsigned short* Btw  = (unsigned short*)((float*)hb + 320000);   // 131,072 f
  unsigned short* Wc1T = (unsigned short*)((float*)Btw + 131072);  // 36,864 f
  unsigned short* Wc2T = (unsigned short*)((float*)Wc1T + 36864);  // 9,216 f
  float* R1 = (float*)Wc2T + 9216;                 // shared scratch region
  unsigned short* A1b = (unsigned short*)R1;       // 10.24M ushort (20.5MB)
  unsigned short* A2b = (unsigned short*)R1;       // aliases A1b (after hlayer)

  // fused prep: zero cur + all weight transposes (one dispatch)
  prep_kernel<<<CURB + WTBLK + W1BLK + W2BLK, 256, 0, stream>>>(
      drug_w, root1, basis1, root2, basis2, (int4*)cur, Btw, Wc1T, Wc2T);

  // CSR build
  scatter_kernel<<<(NE + 255) / 256, 256, 0, stream>>>(ei, cur, rec);

  // x = bf16(x_drug @ drug_w) — counted-vmcnt pipelined
  gemm0_mfma<<<NN / 16, 256, 0, stream>>>(x_drug, Btw, xb);

  // layer 1
  agg1e_kernel<<<NN / 4, 256, 0, stream>>>(xb, cur, rec, comp1, A1b);
  hlayer_mfma<<<(NN + 31) / 32, 256, 0, stream>>>(xb, A1b, Wc1T, bias1, hb);

  // layer 2
  agg2e_kernel<<<NN / 4, 256, 0, stream>>>(hb, cur, rec, comp2, A2b);
  out_mfma<<<(NN + 31) / 32, 256, 0, stream>>>(hb, A2b, Wc2T, bias2, out);
}